// Round 22
// baseline (79.355 us; speedup 1.0000x reference)
//
#include <hip/hip_runtime.h>
#include <hip/hip_bf16.h>

// x: (B=4, T=5, C=3, H=128, W=128) fp32 ; R=2 ; D = 60 ; N = 4096
#define BB 4
#define TC 15
#define DD 60
#define NN 4096
#define HH 128
#define DP 64
#define KT 64
#define NWAVE 4
#define QT 64
#define NTILES 64
#define NSPLIT 4
#define L2E 1.4426950408889634f

typedef short s8v __attribute__((ext_vector_type(8)));   // 8 x bf16
typedef ushort u4v __attribute__((ext_vector_type(4)));
typedef float f4v __attribute__((ext_vector_type(4)));
typedef float f2v __attribute__((ext_vector_type(2)));

static __device__ __forceinline__ ushort f2bf_bits(float f) {
    __hip_bfloat16 h = __float2bfloat16(f);
    return *reinterpret_cast<ushort*>(&h);
}
// truncating f32->bf16 (1 op). P-only: the downward bias feeds both PV numerator
// and l denominator and cancels in the division.
static __device__ __forceinline__ ushort f2bf_trunc(float f) {
    return (ushort)(__float_as_uint(f) >> 16);
}
static __device__ __forceinline__ float bf2f_lo(uint u) { return __uint_as_float(u << 16); }
static __device__ __forceinline__ float bf2f_hi(uint u) { return __uint_as_float(u & 0xFFFF0000u); }
static __device__ __forceinline__ float bf2f(ushort w) { return __uint_as_float((uint)w << 16); }

// ---------- K1: x -> xf_bf (B,D,N) + xf_t (B,N,64) + rnorm + per-batch max norm ----------
__global__ __launch_bounds__(256) void k_prep(const float* __restrict__ x,
                                              ushort* __restrict__ xf_bf,
                                              ushort* __restrict__ xf_t,
                                              float* __restrict__ rnorm,
                                              uint* __restrict__ mxbits) {
    int ng = blockIdx.x * 256 + threadIdx.x;           // b*N + n (blocks never cross b)
    int b = ng >> 12, n = ng & (NN - 1);
    int oh = n >> 6, ow = n & 63;
    const float* xb = x + (size_t)b * TC * HH * HH;
    ushort* xbf = xf_bf + (size_t)b * DD * NN + n;
    ushort row[DP];
    float ss = 0.f;
    #pragma unroll
    for (int d = 0; d < DD; ++d) {
        int c1 = d >> 2, r1 = (d >> 1) & 1, r2 = d & 1;
        float v = xb[(c1 * HH + oh * 2 + r1) * HH + ow * 2 + r2];
        ushort w = f2bf_bits(v);
        row[d] = w;
        float f = bf2f(w);
        ss = fmaf(f, f, ss);
        xbf[(size_t)d * NN] = w;                       // coalesced across lanes
    }
    #pragma unroll
    for (int d = DD; d < DP; ++d) row[d] = 0;
    ushort* dst = xf_t + (size_t)ng * DP;
    #pragma unroll
    for (int j = 0; j < 8; ++j)
        *(s8v*)&dst[j * 8] = *(const s8v*)&row[j * 8];
    float norm = sqrtf(ss) * 1.0002f;                  // safety margin: m must bound row max
    rnorm[ng] = norm;
    float mv = norm;
    #pragma unroll
    for (int off = 1; off < 64; off <<= 1) mv = fmaxf(mv, __shfl_xor(mv, off));
    if ((threadIdx.x & 63) == 0) atomicMax(&mxbits[b], __float_as_uint(mv));
}

// ---------- K2: G (B,64,N) bf16; rows 0..59 = g_w.xf + g_b; row 60 = 1.0 (l column);
// rows 61..63 = 0. 64-row layout removes all branches from attn's staging. ----------
__global__ __launch_bounds__(256) void k_gproj(const ushort* __restrict__ xf_bf,
                                               const float* __restrict__ g_w,
                                               const float* __restrict__ g_b,
                                               ushort* __restrict__ G_bf) {
    int u = blockIdx.x * 256 + threadIdx.x;            // over B*64*N/2
    int idx = u * 2;
    int n = idx & (NN - 1);
    int o = (idx >> 12) & 63;                          // block-uniform
    int b = idx / (DP * NN);
    uint pack;
    if (o < DD) {
        const ushort* X = xf_bf + (size_t)b * DD * NN;
        float a0 = g_b[o], a1 = a0;
        #pragma unroll
        for (int d = 0; d < DD; ++d) {
            uint w = *(const uint*)&X[d * NN + n];
            float gw = g_w[o * DD + d];
            a0 += gw * bf2f_lo(w);
            a1 += gw * bf2f_hi(w);
        }
        pack = (uint)f2bf_bits(a0) | ((uint)f2bf_bits(a1) << 16);
    } else if (o == DD) {
        pack = 0x3F803F80u;                            // 1.0, 1.0
    } else {
        pack = 0u;
    }
    *(uint*)&G_bf[idx] = pack;
}

// ---------- K3: flash attention, split-K=4 (was 8). 1024 blocks x 16 tiles: all 4
// blocks/CU resident (LDS 24KB fits 6), halved epilogue O writes, 2x prologue
// amortization. LDS single-buffer, 2 barriers/tile, reg-prefetch, P/PV interleave.
// m_n = rnorm[n]*mxnorm[b] fixed softmax shift; l folded via G row 60 == 1.0.
// ALL NS write unnormalized O_bf (+l col); k_cout divides.
template <int NS>
__global__ __launch_bounds__(256, 2) void k_attn(const ushort* __restrict__ xf_t,
                                                 const ushort* __restrict__ G_bf,  // (B,64,N)
                                                 const float* __restrict__ rnorm,
                                                 const uint* __restrict__ mxbits,
                                                 ushort* __restrict__ O_bf) {  // (s,b,64,N) bf16
    __shared__ char K_lds[KT * 128];                   // 8 KB
    __shared__ char G_lds[DP * 128];                   // 8 KB
    __shared__ char P_lds[NWAVE][16 * 128];            // 8 KB

    int p = blockIdx.x;
    int s, b, q0;
    if (NS == NSPLIT) {
        // XCD-aware: xcd = p&7; each XCD pair-half owns one batch (~1MB = L2-hot)
        int xcd = p & 7, slot = p >> 3;                // slot in [0,128)
        b = xcd >> 1;
        s = (xcd & 1) * 2 + (slot >> 6);               // NS=4: 2 splits per xcd-half
        q0 = (slot & 63) * QT;
    } else {
        s = 0;
        b = p >> 6;
        q0 = (p & 63) * QT;
    }
    int tid = threadIdx.x;
    int lane = tid & 63, wv = tid >> 6;
    int r = lane & 15, g = lane >> 4;

    const ushort* Xt = xf_t + (size_t)b * NN * DP;
    const ushort* Gb = G_bf + (size_t)b * DP * NN;

    int qrow = q0 + wv * 16 + r;
    s8v qa[2];
    qa[0] = *(const s8v*)&Xt[(size_t)qrow * DP + g * 8];
    qa[1] = *(const s8v*)&Xt[(size_t)qrow * DP + 32 + g * 8];

    // fixed per-row shift, rows 4g+0..3 of this lane
    float mx = __uint_as_float(mxbits[b]);
    float nm[4];
    #pragma unroll
    for (int reg = 0; reg < 4; ++reg)
        nm[reg] = -rnorm[b * NN + q0 + wv * 16 + 4 * g + reg] * mx * L2E;

    f4v of[4];
    #pragma unroll
    for (int i = 0; i < 4; ++i) of[i] = (f4v){0.f, 0.f, 0.f, 0.f};

    // staging: 256 threads x two 16B units per buffer; row = e>>3, j = e&7
    const int e0 = tid, e1 = 256 + tid;
    const int kr0 = e0 >> 3, kj0 = e0 & 7;             // rows 0..31
    const int kr1 = e1 >> 3, kj1 = e1 & 7;             // rows 32..63
    const int kw0 = (kr0 * 128 + kj0 * 16) ^ ((kr0 & 7) << 4);
    const int kw1 = (kr1 * 128 + kj1 * 16) ^ ((kr1 & 7) << 4);
    s8v kp0, kp1, gp0, gp1;

    auto stage_regs = [&](int t) {
        int n0 = t * KT;
        kp0 = *(const s8v*)&Xt[(size_t)(n0 + kr0) * DP + kj0 * 8];
        kp1 = *(const s8v*)&Xt[(size_t)(n0 + kr1) * DP + kj1 * 8];
        gp0 = *(const s8v*)&Gb[(size_t)kr0 * NN + n0 + kj0 * 8];   // branch-free: 64 rows
        gp1 = *(const s8v*)&Gb[(size_t)kr1 * NN + n0 + kj1 * 8];
    };
    auto lds_write = [&]() {
        *(s8v*)(K_lds + kw0) = kp0;
        *(s8v*)(K_lds + kw1) = kp1;
        *(s8v*)(G_lds + kw0) = gp0;
        *(s8v*)(G_lds + kw1) = gp1;
    };

    const int t0 = s * (NTILES / NS);
    const int tend = t0 + NTILES / NS;
    char* Pw = P_lds[wv];

    stage_regs(t0);
    lds_write();
    __syncthreads();

    #pragma unroll 1
    for (int t = t0; t < tend; ++t) {
        bool more = (t + 1 < tend);
        if (more) stage_regs(t + 1);          // global loads in flight during compute

        // ---- S = Q.K^T ----
        f4v sf[4];
        #pragma unroll
        for (int i = 0; i < 4; ++i) sf[i] = (f4v){0.f, 0.f, 0.f, 0.f};
        __builtin_amdgcn_s_setprio(1);
        #pragma unroll
        for (int kt2 = 0; kt2 < 4; ++kt2)
            #pragma unroll
            for (int kb = 0; kb < 2; ++kb) {
                int off = (((kt2 * 16 + r) * 128) + kb * 64 + g * 16) ^ ((r & 7) << 4);
                s8v bf = *(const s8v*)(K_lds + off);
                sf[kt2] = __builtin_amdgcn_mfma_f32_16x16x32_bf16(qa[kb], bf, sf[kt2], 0, 0, 0);
            }
        __builtin_amdgcn_s_setprio(0);

        // ---- P for keys 0..31 (kt2 = 0,1), truncating cvt ----
        #pragma unroll
        for (int kt2 = 0; kt2 < 2; ++kt2)
            #pragma unroll
            for (int reg = 0; reg < 4; ++reg) {
                float pv = __builtin_exp2f(fmaf(sf[kt2][reg], L2E, nm[reg]));
                int row = 4 * g + reg;
                int boff = ((row * 128) + kt2 * 32 + 2 * r) ^ ((row & 7) << 4);
                *(ushort*)(Pw + boff) = f2bf_trunc(pv);
            }
        // ---- PV kb=0 (wave-internal LDS is in-order; overlaps next P block) ----
        {
            int poff = ((r * 128) + g * 16) ^ ((r & 7) << 4);
            s8v pa = *(const s8v*)(Pw + poff);
            __builtin_amdgcn_s_setprio(1);
            #pragma unroll
            for (int ot = 0; ot < 4; ++ot) {
                int goff = (((ot * 16 + r) * 128) + g * 16) ^ ((r & 7) << 4);
                s8v gf = *(const s8v*)(G_lds + goff);
                of[ot] = __builtin_amdgcn_mfma_f32_16x16x32_bf16(pa, gf, of[ot], 0, 0, 0);
            }
            __builtin_amdgcn_s_setprio(0);
        }
        // ---- P for keys 32..63 (kt2 = 2,3), truncating cvt ----
        #pragma unroll
        for (int kt2 = 2; kt2 < 4; ++kt2)
            #pragma unroll
            for (int reg = 0; reg < 4; ++reg) {
                float pv = __builtin_exp2f(fmaf(sf[kt2][reg], L2E, nm[reg]));
                int row = 4 * g + reg;
                int boff = ((row * 128) + kt2 * 32 + 2 * r) ^ ((row & 7) << 4);
                *(ushort*)(Pw + boff) = f2bf_trunc(pv);
            }
        // ---- PV kb=1 ----
        {
            int poff = ((r * 128) + 64 + g * 16) ^ ((r & 7) << 4);
            s8v pa = *(const s8v*)(Pw + poff);
            __builtin_amdgcn_s_setprio(1);
            #pragma unroll
            for (int ot = 0; ot < 4; ++ot) {
                int goff = (((ot * 16 + r) * 128) + 64 + g * 16) ^ ((r & 7) << 4);
                s8v gf = *(const s8v*)(G_lds + goff);
                of[ot] = __builtin_amdgcn_mfma_f32_16x16x32_bf16(pa, gf, of[ot], 0, 0, 0);
            }
            __builtin_amdgcn_s_setprio(0);
        }

        if (more) {
            __syncthreads();                  // all waves done reading K/G
            lds_write();
            __syncthreads();                  // next tile staged
        }
    }

    // unified epilogue: unnormalized O (+ l in col 60) for all NS; k_cout divides
    int qb = q0 + wv * 16 + 4 * g;
    ushort* Ob = O_bf + ((size_t)(s * BB + b) * DP) * NN;
    #pragma unroll
    for (int ot = 0; ot < 4; ++ot) {
        int o = ot * 16 + r;
        u4v v = {f2bf_bits(of[ot][0]), f2bf_bits(of[ot][1]),
                 f2bf_bits(of[ot][2]), f2bf_bits(of[ot][3])};
        *(u4v*)&Ob[(size_t)o * NN + qb] = v;                 // coalesced 32B per r-group
    }
}

// ---------- K4 (fused combine+out): block per 32 pixels. Phase 1: sum NS splits
// into y_lds[32][61] f32 (stride 61 -> bank-free) + linv from l col (o=60).
// Phase 2: out[o] = (ww[o].y)*linv + wb[o] + x, written pixel-shuffled.
template <int NS>
__global__ __launch_bounds__(256) void k_cout(const ushort* __restrict__ O_bf,
                                              const float* __restrict__ w_w,
                                              const float* __restrict__ w_b,
                                              const float* __restrict__ x,
                                              float* __restrict__ out) {
    __shared__ float ww[DD * DD];                      // 14.4 KB
    __shared__ float wb[DD];
    __shared__ float ylds[32][61];                     // 7.8 KB
    __shared__ float linv[32];

    int b  = blockIdx.x >> 7;                          // grid = BB*128
    int n0 = (blockIdx.x & 127) * 32;
    int tid = threadIdx.x;
    for (int i = tid; i < DD * DD; i += 256) ww[i] = w_w[i];
    if (tid < DD) wb[tid] = w_b[tid];

    int pix  = tid & 31;
    int ogrp = tid >> 5;                               // 0..7
    int n = n0 + pix;

    // ---- phase 1: y[pix][o] = sum_s O_s[o][n] ; linv[pix] = 1/sum_s O_s[60][n] ----
    const ushort* Op = O_bf + (size_t)b * DP * NN + n;
    #pragma unroll
    for (int i = 0; i < 8; ++i) {
        int o = ogrp * 8 + i;                          // 0..63
        if (o > DD) continue;                          // o<=60 processed
        float sum = 0.f;
        #pragma unroll
        for (int ss = 0; ss < NS; ++ss)
            sum += bf2f(Op[(size_t)ss * BB * DP * NN + (size_t)o * NN]);
        if (o < DD) ylds[pix][o] = sum;
        else        linv[pix] = 1.0f / sum;            // o == 60
    }
    __syncthreads();

    // ---- phase 2: 8 outputs per thread (o = 8k+ogrp), ww from LDS, y from LDS ----
    float li = linv[pix];
    int oh = n >> 6, ow = n & 63;
    #pragma unroll
    for (int k = 0; k < 8; ++k) {
        int o = k * 8 + ogrp;
        if (o < DD) {
            float acc = 0.f;
            #pragma unroll
            for (int d = 0; d < DD; ++d)
                acc = fmaf(ww[o * DD + d], ylds[pix][d], acc);
            int c1 = o >> 2, r1 = (o >> 1) & 1, r2 = o & 1;
            size_t xi = ((size_t)(b * TC + c1) * HH + 2 * oh + r1) * HH + 2 * ow + r2;
            out[xi] = fmaf(acc, li, wb[o]) + x[xi];
        }
    }
}

extern "C" void kernel_launch(void* const* d_in, const int* in_sizes, int n_in,
                              void* d_out, int out_size, void* d_ws, size_t ws_size,
                              hipStream_t stream) {
    const float* x   = (const float*)d_in[0];
    const float* g_w = (const float*)d_in[1];
    const float* g_b = (const float*)d_in[2];
    const float* w_w = (const float*)d_in[3];
    const float* w_b = (const float*)d_in[4];
    float* out = (float*)d_out;

    char* ws = (char*)d_ws;
    ushort* xf_bf  = (ushort*)ws;                      // 1,966,080 B
    ushort* xf_t   = (ushort*)(ws + 1966080);          // 2,097,152 B
    ushort* G_bf   = (ushort*)(ws + 4063232);          // 2,097,152 B (B,64,N)
    float*  rnorm  = (float*)(ws + 6160384);           // 65,536 B
    uint*   mxbits = (uint*)(ws + 6225920);            // 256 B (16 used)
    ushort* O_bf   = (ushort*)(ws + 6226176);          // 8,388,608 B (NS=4) -> end 14,614,784
    const size_t SPLIT_NEED = 14614784;

    hipMemsetAsync(mxbits, 0, BB * sizeof(uint), stream);
    k_prep<<<BB * NN / 256, 256, 0, stream>>>(x, xf_bf, xf_t, rnorm, mxbits);
    k_gproj<<<BB * DP * NN / 512, 256, 0, stream>>>(xf_bf, g_w, g_b, G_bf);

    if (ws_size >= SPLIT_NEED) {
        k_attn<NSPLIT><<<NSPLIT * BB * (NN / QT), 256, 0, stream>>>(
            xf_t, G_bf, rnorm, mxbits, O_bf);
        k_cout<NSPLIT><<<BB * 128, 256, 0, stream>>>(O_bf, w_w, w_b, x, out);
    } else {
        k_attn<1><<<BB * (NN / QT), 256, 0, stream>>>(
            xf_t, G_bf, rnorm, mxbits, O_bf);
        k_cout<1><<<BB * 128, 256, 0, stream>>>(O_bf, w_w, w_b, x, out);
    }
}

// Round 23
// 72.510 us; speedup vs baseline: 1.0944x; 1.0944x over previous
//
#include <hip/hip_runtime.h>
#include <hip/hip_bf16.h>

// x: (B=4, T=5, C=3, H=128, W=128) fp32 ; R=2 ; D = 60 ; N = 4096
#define BB 4
#define TC 15
#define DD 60
#define NN 4096
#define HH 128
#define DP 64
#define KT 64
#define NWAVE 4
#define QT 64
#define NTILES 64
#define NSPLIT 4
#define L2E 1.4426950408889634f

typedef short s8v __attribute__((ext_vector_type(8)));   // 8 x bf16
typedef ushort u4v __attribute__((ext_vector_type(4)));
typedef float f4v __attribute__((ext_vector_type(4)));
typedef float f2v __attribute__((ext_vector_type(2)));

static __device__ __forceinline__ ushort f2bf_bits(float f) {
    __hip_bfloat16 h = __float2bfloat16(f);
    return *reinterpret_cast<ushort*>(&h);
}
// truncating f32->bf16 (1 op). P-only: bias cancels between numerator and l.
static __device__ __forceinline__ ushort f2bf_trunc(float f) {
    return (ushort)(__float_as_uint(f) >> 16);
}
static __device__ __forceinline__ float bf2f(ushort w) { return __uint_as_float((uint)w << 16); }

// ---------- K1: x -> xf2 (B,64,N) bf16 [rows 0..59 = xf, 60 = 1.0, 61..63 = 0]
//                 + xf_t (B,N,64) + rnorm + per-batch max norm ----------
__global__ __launch_bounds__(256) void k_prep(const float* __restrict__ x,
                                              ushort* __restrict__ xf2,
                                              ushort* __restrict__ xf_t,
                                              float* __restrict__ rnorm,
                                              uint* __restrict__ mxbits) {
    int ng = blockIdx.x * 256 + threadIdx.x;           // b*N + n (blocks never cross b)
    int b = ng >> 12, n = ng & (NN - 1);
    int oh = n >> 6, ow = n & 63;
    const float* xb = x + (size_t)b * TC * HH * HH;
    ushort* x2 = xf2 + (size_t)b * DP * NN + n;
    ushort row[DP];
    float ss = 0.f;
    #pragma unroll
    for (int d = 0; d < DD; ++d) {
        int c1 = d >> 2, r1 = (d >> 1) & 1, r2 = d & 1;
        float v = xb[(c1 * HH + oh * 2 + r1) * HH + ow * 2 + r2];
        ushort w = f2bf_bits(v);
        row[d] = w;
        float f = bf2f(w);
        ss = fmaf(f, f, ss);
        x2[(size_t)d * NN] = w;                        // coalesced across lanes
    }
    x2[(size_t)60 * NN] = (ushort)0x3F80;              // ones row -> l accumulator
    x2[(size_t)61 * NN] = 0;
    x2[(size_t)62 * NN] = 0;
    x2[(size_t)63 * NN] = 0;
    #pragma unroll
    for (int d = DD; d < DP; ++d) row[d] = 0;
    ushort* dst = xf_t + (size_t)ng * DP;
    #pragma unroll
    for (int j = 0; j < 8; ++j)
        *(s8v*)&dst[j * 8] = *(const s8v*)&row[j * 8];
    float norm = sqrtf(ss) * 1.0002f;                  // safety margin: m must bound row max
    rnorm[ng] = norm;
    float mv = norm;
    #pragma unroll
    for (int off = 1; off < 64; off <<= 1) mv = fmaxf(mv, __shfl_xor(mv, off));
    if ((threadIdx.x & 63) == 0) atomicMax(&mxbits[b], __float_as_uint(mv));
}

// ---------- K2 (tiny): M = w_w . g_w  (60x60, fp32) ; c = w_w . g_b + w_b (60) ----------
// Algebra: out = w_w.(Y) + w_b with Y = (Z/l).g_w^T + g_b^T  ==>  out = (Z/l).M^T + c.
__global__ __launch_bounds__(256) void k_mw(const float* __restrict__ g_w,
                                            const float* __restrict__ g_b,
                                            const float* __restrict__ w_w,
                                            const float* __restrict__ w_b,
                                            float* __restrict__ Mc) {   // [3600 M][60 c]
    int idx = blockIdx.x * 256 + threadIdx.x;
    if (idx < DD * DD) {
        int p = idx / DD, d = idx % DD;
        float acc = 0.f;
        #pragma unroll
        for (int o = 0; o < DD; ++o)
            acc = fmaf(w_w[p * DD + o], g_w[o * DD + d], acc);
        Mc[idx] = acc;
    } else if (idx < DD * DD + DD) {
        int p = idx - DD * DD;
        float acc = w_b[p];
        #pragma unroll
        for (int o = 0; o < DD; ++o)
            acc = fmaf(w_w[p * DD + o], g_b[o], acc);
        Mc[idx] = acc;
    }
}

// ---------- K3: flash attention, split-K=4. Computes Z = P.X^T (NOT P.G^T): the
// B-operand tile is xf2 (B,64,N) — row 60 = 1.0 accumulates l. g_w is applied in
// k_cout via M (algebraic commutation; kernel body identical to r22's proven one).
// LDS single-buffer 24KB, 2 barriers/tile, reg-prefetch, P/PV interleave.
// m_n = rnorm[n]*mxnorm[b] fixed softmax shift (Cauchy-Schwarz upper bound).
template <int NS>
__global__ __launch_bounds__(256, 2) void k_attn(const ushort* __restrict__ xf_t,
                                                 const ushort* __restrict__ x2_bf, // (B,64,N)
                                                 const float* __restrict__ rnorm,
                                                 const uint* __restrict__ mxbits,
                                                 ushort* __restrict__ O_bf) {  // (s,b,64,N) bf16
    __shared__ char K_lds[KT * 128];                   // 8 KB
    __shared__ char G_lds[DP * 128];                   // 8 KB (X^T tile)
    __shared__ char P_lds[NWAVE][16 * 128];            // 8 KB

    int p = blockIdx.x;
    int s, b, q0;
    if (NS == NSPLIT) {
        // XCD-aware: xcd = p&7; each XCD pair-half owns one batch (~1MB = L2-hot)
        int xcd = p & 7, slot = p >> 3;                // slot in [0,128)
        b = xcd >> 1;
        s = (xcd & 1) * 2 + (slot >> 6);               // NS=4: 2 splits per xcd-half
        q0 = (slot & 63) * QT;
    } else {
        s = 0;
        b = p >> 6;
        q0 = (p & 63) * QT;
    }
    int tid = threadIdx.x;
    int lane = tid & 63, wv = tid >> 6;
    int r = lane & 15, g = lane >> 4;

    const ushort* Xt = xf_t + (size_t)b * NN * DP;
    const ushort* Gb = x2_bf + (size_t)b * DP * NN;

    int qrow = q0 + wv * 16 + r;
    s8v qa[2];
    qa[0] = *(const s8v*)&Xt[(size_t)qrow * DP + g * 8];
    qa[1] = *(const s8v*)&Xt[(size_t)qrow * DP + 32 + g * 8];

    // fixed per-row shift, rows 4g+0..3 of this lane
    float mx = __uint_as_float(mxbits[b]);
    float nm[4];
    #pragma unroll
    for (int reg = 0; reg < 4; ++reg)
        nm[reg] = -rnorm[b * NN + q0 + wv * 16 + 4 * g + reg] * mx * L2E;

    f4v of[4];
    #pragma unroll
    for (int i = 0; i < 4; ++i) of[i] = (f4v){0.f, 0.f, 0.f, 0.f};

    // staging: 256 threads x two 16B units per buffer; row = e>>3, j = e&7
    const int e0 = tid, e1 = 256 + tid;
    const int kr0 = e0 >> 3, kj0 = e0 & 7;             // rows 0..31
    const int kr1 = e1 >> 3, kj1 = e1 & 7;             // rows 32..63
    const int kw0 = (kr0 * 128 + kj0 * 16) ^ ((kr0 & 7) << 4);
    const int kw1 = (kr1 * 128 + kj1 * 16) ^ ((kr1 & 7) << 4);
    s8v kp0, kp1, gp0, gp1;

    auto stage_regs = [&](int t) {
        int n0 = t * KT;
        kp0 = *(const s8v*)&Xt[(size_t)(n0 + kr0) * DP + kj0 * 8];
        kp1 = *(const s8v*)&Xt[(size_t)(n0 + kr1) * DP + kj1 * 8];
        gp0 = *(const s8v*)&Gb[(size_t)kr0 * NN + n0 + kj0 * 8];   // branch-free: 64 rows
        gp1 = *(const s8v*)&Gb[(size_t)kr1 * NN + n0 + kj1 * 8];
    };
    auto lds_write = [&]() {
        *(s8v*)(K_lds + kw0) = kp0;
        *(s8v*)(K_lds + kw1) = kp1;
        *(s8v*)(G_lds + kw0) = gp0;
        *(s8v*)(G_lds + kw1) = gp1;
    };

    const int t0 = s * (NTILES / NS);
    const int tend = t0 + NTILES / NS;
    char* Pw = P_lds[wv];

    stage_regs(t0);
    lds_write();
    __syncthreads();

    #pragma unroll 1
    for (int t = t0; t < tend; ++t) {
        bool more = (t + 1 < tend);
        if (more) stage_regs(t + 1);          // global loads in flight during compute

        // ---- S = Q.K^T ----
        f4v sf[4];
        #pragma unroll
        for (int i = 0; i < 4; ++i) sf[i] = (f4v){0.f, 0.f, 0.f, 0.f};
        __builtin_amdgcn_s_setprio(1);
        #pragma unroll
        for (int kt2 = 0; kt2 < 4; ++kt2)
            #pragma unroll
            for (int kb = 0; kb < 2; ++kb) {
                int off = (((kt2 * 16 + r) * 128) + kb * 64 + g * 16) ^ ((r & 7) << 4);
                s8v bf = *(const s8v*)(K_lds + off);
                sf[kt2] = __builtin_amdgcn_mfma_f32_16x16x32_bf16(qa[kb], bf, sf[kt2], 0, 0, 0);
            }
        __builtin_amdgcn_s_setprio(0);

        // ---- P for keys 0..31 (kt2 = 0,1), truncating cvt ----
        #pragma unroll
        for (int kt2 = 0; kt2 < 2; ++kt2)
            #pragma unroll
            for (int reg = 0; reg < 4; ++reg) {
                float pv = __builtin_exp2f(fmaf(sf[kt2][reg], L2E, nm[reg]));
                int row = 4 * g + reg;
                int boff = ((row * 128) + kt2 * 32 + 2 * r) ^ ((row & 7) << 4);
                *(ushort*)(Pw + boff) = f2bf_trunc(pv);
            }
        // ---- Z += P.X^T kb=0 (wave-internal LDS is in-order) ----
        {
            int poff = ((r * 128) + g * 16) ^ ((r & 7) << 4);
            s8v pa = *(const s8v*)(Pw + poff);
            __builtin_amdgcn_s_setprio(1);
            #pragma unroll
            for (int ot = 0; ot < 4; ++ot) {
                int goff = (((ot * 16 + r) * 128) + g * 16) ^ ((r & 7) << 4);
                s8v gf = *(const s8v*)(G_lds + goff);
                of[ot] = __builtin_amdgcn_mfma_f32_16x16x32_bf16(pa, gf, of[ot], 0, 0, 0);
            }
            __builtin_amdgcn_s_setprio(0);
        }
        // ---- P for keys 32..63 (kt2 = 2,3), truncating cvt ----
        #pragma unroll
        for (int kt2 = 2; kt2 < 4; ++kt2)
            #pragma unroll
            for (int reg = 0; reg < 4; ++reg) {
                float pv = __builtin_exp2f(fmaf(sf[kt2][reg], L2E, nm[reg]));
                int row = 4 * g + reg;
                int boff = ((row * 128) + kt2 * 32 + 2 * r) ^ ((row & 7) << 4);
                *(ushort*)(Pw + boff) = f2bf_trunc(pv);
            }
        // ---- Z += P.X^T kb=1 ----
        {
            int poff = ((r * 128) + 64 + g * 16) ^ ((r & 7) << 4);
            s8v pa = *(const s8v*)(Pw + poff);
            __builtin_amdgcn_s_setprio(1);
            #pragma unroll
            for (int ot = 0; ot < 4; ++ot) {
                int goff = (((ot * 16 + r) * 128) + 64 + g * 16) ^ ((r & 7) << 4);
                s8v gf = *(const s8v*)(G_lds + goff);
                of[ot] = __builtin_amdgcn_mfma_f32_16x16x32_bf16(pa, gf, of[ot], 0, 0, 0);
            }
            __builtin_amdgcn_s_setprio(0);
        }

        if (more) {
            __syncthreads();                  // all waves done reading K/X^T
            lds_write();
            __syncthreads();                  // next tile staged
        }
    }

    // epilogue: unnormalized Z (+ l in col 60); k_cout applies M and divides
    int qb = q0 + wv * 16 + 4 * g;
    ushort* Ob = O_bf + ((size_t)(s * BB + b) * DP) * NN;
    #pragma unroll
    for (int ot = 0; ot < 4; ++ot) {
        int o = ot * 16 + r;
        u4v v = {f2bf_bits(of[ot][0]), f2bf_bits(of[ot][1]),
                 f2bf_bits(of[ot][2]), f2bf_bits(of[ot][3])};
        *(u4v*)&Ob[(size_t)o * NN + qb] = v;                 // coalesced 32B per r-group
    }
}

// ---------- K4 (fused combine+out): block per 32 pixels. Phase 1: sum NS splits
// into z_lds[32][61] f32 (stride 61 -> bank-free) + linv from l col (o=60).
// Phase 2: out[p] = (M[p].z)*linv + c[p] + x, written pixel-shuffled.
template <int NS>
__global__ __launch_bounds__(256) void k_cout(const ushort* __restrict__ O_bf,
                                              const float* __restrict__ Mc,
                                              const float* __restrict__ x,
                                              float* __restrict__ out) {
    __shared__ float ww[DD * DD];                      // 14.4 KB (= M)
    __shared__ float wb[DD];                           //          (= c)
    __shared__ float zlds[32][61];                     // 7.8 KB
    __shared__ float linv[32];

    int b  = blockIdx.x >> 7;                          // grid = BB*128
    int n0 = (blockIdx.x & 127) * 32;
    int tid = threadIdx.x;
    for (int i = tid; i < DD * DD; i += 256) ww[i] = Mc[i];
    if (tid < DD) wb[tid] = Mc[DD * DD + tid];

    int pix  = tid & 31;
    int ogrp = tid >> 5;                               // 0..7
    int n = n0 + pix;

    // ---- phase 1: z[pix][d] = sum_s Z_s[d][n] ; linv[pix] = 1/sum_s Z_s[60][n] ----
    const ushort* Op = O_bf + (size_t)b * DP * NN + n;
    #pragma unroll
    for (int i = 0; i < 8; ++i) {
        int o = ogrp * 8 + i;                          // 0..63
        if (o > DD) continue;                          // o<=60 processed
        float sum = 0.f;
        #pragma unroll
        for (int ss = 0; ss < NS; ++ss)
            sum += bf2f(Op[(size_t)ss * BB * DP * NN + (size_t)o * NN]);
        if (o < DD) zlds[pix][o] = sum;
        else        linv[pix] = 1.0f / sum;            // o == 60
    }
    __syncthreads();

    // ---- phase 2: 8 outputs per thread (p = 8k+ogrp), M from LDS, z from LDS ----
    float li = linv[pix];
    int oh = n >> 6, ow = n & 63;
    #pragma unroll
    for (int k = 0; k < 8; ++k) {
        int o = k * 8 + ogrp;
        if (o < DD) {
            float acc = 0.f;
            #pragma unroll
            for (int d = 0; d < DD; ++d)
                acc = fmaf(ww[o * DD + d], zlds[pix][d], acc);
            int c1 = o >> 2, r1 = (o >> 1) & 1, r2 = o & 1;
            size_t xi = ((size_t)(b * TC + c1) * HH + 2 * oh + r1) * HH + 2 * ow + r2;
            out[xi] = fmaf(acc, li, wb[o]) + x[xi];
        }
    }
}

extern "C" void kernel_launch(void* const* d_in, const int* in_sizes, int n_in,
                              void* d_out, int out_size, void* d_ws, size_t ws_size,
                              hipStream_t stream) {
    const float* x   = (const float*)d_in[0];
    const float* g_w = (const float*)d_in[1];
    const float* g_b = (const float*)d_in[2];
    const float* w_w = (const float*)d_in[3];
    const float* w_b = (const float*)d_in[4];
    float* out = (float*)d_out;

    char* ws = (char*)d_ws;
    ushort* xf2    = (ushort*)ws;                      // 2,097,152 B (B,64,N)
    ushort* xf_t   = (ushort*)(ws + 2097152);          // 2,097,152 B (B,N,64)
    float*  rnorm  = (float*)(ws + 4194304);           // 65,536 B
    uint*   mxbits = (uint*)(ws + 4259840);            // 256 B
    float*  Mc     = (float*)(ws + 4260096);           // 16,384 B  (3600 M + 60 c)
    ushort* O_bf   = (ushort*)(ws + 4276480);          // 8,388,608 B (NS=4) -> end 12,665,088
    const size_t SPLIT_NEED = 12665088;

    hipMemsetAsync(mxbits, 0, BB * sizeof(uint), stream);
    k_prep<<<BB * NN / 256, 256, 0, stream>>>(x, xf2, xf_t, rnorm, mxbits);
    k_mw<<<16, 256, 0, stream>>>(g_w, g_b, w_w, w_b, Mc);

    if (ws_size >= SPLIT_NEED) {
        k_attn<NSPLIT><<<NSPLIT * BB * (NN / QT), 256, 0, stream>>>(
            xf_t, xf2, rnorm, mxbits, O_bf);
        k_cout<NSPLIT><<<BB * 128, 256, 0, stream>>>(O_bf, Mc, x, out);
    } else {
        k_attn<1><<<BB * (NN / QT), 256, 0, stream>>>(
            xf_t, xf2, rnorm, mxbits, O_bf);
        k_cout<1><<<BB * 128, 256, 0, stream>>>(O_bf, Mc, x, out);
    }
}

// Round 24
// 69.361 us; speedup vs baseline: 1.1441x; 1.0454x over previous
//
#include <hip/hip_runtime.h>
#include <hip/hip_bf16.h>

// x: (B=4, T=5, C=3, H=128, W=128) fp32 ; R=2 ; D = 60 ; N = 4096
#define BB 4
#define TC 15
#define DD 60
#define NN 4096
#define HH 128
#define DP 64
#define KT 64
#define NWAVE 4
#define QT 64
#define NTILES 64
#define NSPLIT 4
#define L2E 1.4426950408889634f

typedef short s8v __attribute__((ext_vector_type(8)));   // 8 x bf16
typedef ushort u4v __attribute__((ext_vector_type(4)));
typedef float f4v __attribute__((ext_vector_type(4)));
typedef float f2v __attribute__((ext_vector_type(2)));

static __device__ __forceinline__ ushort f2bf_bits(float f) {
    __hip_bfloat16 h = __float2bfloat16(f);
    return *reinterpret_cast<ushort*>(&h);
}
// truncating f32->bf16 (1 op). P-only: bias cancels between numerator and l.
static __device__ __forceinline__ ushort f2bf_trunc(float f) {
    return (ushort)(__float_as_uint(f) >> 16);
}
static __device__ __forceinline__ float bf2f(ushort w) { return __uint_as_float((uint)w << 16); }

// ---------- K0 (tiny, launched FIRST): zero mxbits + M = w_w.g_w ; c = w_w.g_b + w_b ----------
// Algebra: out = w_w.Y + w_b with Y = (Z/l).g_w^T + g_b^T  ==>  out = (Z/l).M^T + c.
__global__ __launch_bounds__(256) void k_mw(const float* __restrict__ g_w,
                                            const float* __restrict__ g_b,
                                            const float* __restrict__ w_w,
                                            const float* __restrict__ w_b,
                                            float* __restrict__ Mc,     // [3600 M][60 c]
                                            uint* __restrict__ mxbits) {
    int idx = blockIdx.x * 256 + threadIdx.x;
    if (idx < BB) mxbits[idx] = 0;                     // same-stream: done before k_prep
    if (idx < DD * DD) {
        int p = idx / DD, d = idx % DD;
        float acc = 0.f;
        #pragma unroll
        for (int o = 0; o < DD; ++o)
            acc = fmaf(w_w[p * DD + o], g_w[o * DD + d], acc);
        Mc[idx] = acc;
    } else if (idx < DD * DD + DD) {
        int p = idx - DD * DD;
        float acc = w_b[p];
        #pragma unroll
        for (int o = 0; o < DD; ++o)
            acc = fmaf(w_w[p * DD + o], g_b[o], acc);
        Mc[idx] = acc;
    }
}

// ---------- K1: x -> xf2 (B,64,N) bf16 [rows 0..59 = xf, 60 = 1.0, 61..63 = 0]
//                 + xf_t (B,N,64) + rnorm + per-batch max norm ----------
// f2v loads: d-pairs (r2=0,1) are adjacent floats -> 30 vec2 loads, 8B/lane coalesced.
__global__ __launch_bounds__(256) void k_prep(const float* __restrict__ x,
                                              ushort* __restrict__ xf2,
                                              ushort* __restrict__ xf_t,
                                              float* __restrict__ rnorm,
                                              uint* __restrict__ mxbits) {
    int ng = blockIdx.x * 256 + threadIdx.x;           // b*N + n (blocks never cross b)
    int b = ng >> 12, n = ng & (NN - 1);
    int oh = n >> 6, ow = n & 63;
    const float* xb = x + (size_t)b * TC * HH * HH;
    ushort* x2 = xf2 + (size_t)b * DP * NN + n;
    ushort row[DP];
    float ss = 0.f;
    #pragma unroll
    for (int cr = 0; cr < 30; ++cr) {                  // c1 = cr>>1, r1 = cr&1
        int c1 = cr >> 1, r1 = cr & 1;
        f2v v = *(const f2v*)&xb[(c1 * HH + oh * 2 + r1) * HH + ow * 2];
        int d0 = cr * 2;                               // = c1*4 + r1*2
        ushort w0 = f2bf_bits(v[0]);
        ushort w1 = f2bf_bits(v[1]);
        row[d0] = w0; row[d0 + 1] = w1;
        float f0 = bf2f(w0), f1 = bf2f(w1);
        ss = fmaf(f0, f0, ss);
        ss = fmaf(f1, f1, ss);
        x2[(size_t)d0 * NN] = w0;                      // coalesced across lanes
        x2[(size_t)(d0 + 1) * NN] = w1;
    }
    x2[(size_t)60 * NN] = (ushort)0x3F80;              // ones row -> l accumulator
    x2[(size_t)61 * NN] = 0;
    x2[(size_t)62 * NN] = 0;
    x2[(size_t)63 * NN] = 0;
    #pragma unroll
    for (int d = DD; d < DP; ++d) row[d] = 0;
    ushort* dst = xf_t + (size_t)ng * DP;
    #pragma unroll
    for (int j = 0; j < 8; ++j)
        *(s8v*)&dst[j * 8] = *(const s8v*)&row[j * 8];
    float norm = sqrtf(ss) * 1.0002f;                  // safety margin: m must bound row max
    rnorm[ng] = norm;
    float mv = norm;
    #pragma unroll
    for (int off = 1; off < 64; off <<= 1) mv = fmaxf(mv, __shfl_xor(mv, off));
    if ((threadIdx.x & 63) == 0) atomicMax(&mxbits[b], __float_as_uint(mv));
}

// ---------- K3: flash attention, split-K=4. Z = P.X^T with xf2 row 60 = 1 -> l.
// LDS single-buffer 24KB, 2 barriers/tile, reg-prefetch, P/PV interleave.
// m_n = rnorm[n]*mxnorm[b] fixed softmax shift. s_setprio REMOVED (m190: hurts
// barrier-synced lockstep kernels). ALL NS write unnormalized Z (+l); k_cout divides.
template <int NS>
__global__ __launch_bounds__(256, 2) void k_attn(const ushort* __restrict__ xf_t,
                                                 const ushort* __restrict__ x2_bf, // (B,64,N)
                                                 const float* __restrict__ rnorm,
                                                 const uint* __restrict__ mxbits,
                                                 ushort* __restrict__ O_bf) {  // (s,b,64,N) bf16
    __shared__ char K_lds[KT * 128];                   // 8 KB
    __shared__ char G_lds[DP * 128];                   // 8 KB (X^T tile)
    __shared__ char P_lds[NWAVE][16 * 128];            // 8 KB

    int p = blockIdx.x;
    int s, b, q0;
    if (NS == NSPLIT) {
        // XCD-aware: xcd = p&7; each XCD pair-half owns one batch (~1MB = L2-hot)
        int xcd = p & 7, slot = p >> 3;                // slot in [0,128)
        b = xcd >> 1;
        s = (xcd & 1) * 2 + (slot >> 6);               // NS=4: 2 splits per xcd-half
        q0 = (slot & 63) * QT;
    } else {
        s = 0;
        b = p >> 6;
        q0 = (p & 63) * QT;
    }
    int tid = threadIdx.x;
    int lane = tid & 63, wv = tid >> 6;
    int r = lane & 15, g = lane >> 4;

    const ushort* Xt = xf_t + (size_t)b * NN * DP;
    const ushort* Gb = x2_bf + (size_t)b * DP * NN;

    int qrow = q0 + wv * 16 + r;
    s8v qa[2];
    qa[0] = *(const s8v*)&Xt[(size_t)qrow * DP + g * 8];
    qa[1] = *(const s8v*)&Xt[(size_t)qrow * DP + 32 + g * 8];

    // fixed per-row shift, rows 4g+0..3 of this lane
    float mx = __uint_as_float(mxbits[b]);
    float nm[4];
    #pragma unroll
    for (int reg = 0; reg < 4; ++reg)
        nm[reg] = -rnorm[b * NN + q0 + wv * 16 + 4 * g + reg] * mx * L2E;

    f4v of[4];
    #pragma unroll
    for (int i = 0; i < 4; ++i) of[i] = (f4v){0.f, 0.f, 0.f, 0.f};

    // staging: 256 threads x two 16B units per buffer; row = e>>3, j = e&7
    const int e0 = tid, e1 = 256 + tid;
    const int kr0 = e0 >> 3, kj0 = e0 & 7;             // rows 0..31
    const int kr1 = e1 >> 3, kj1 = e1 & 7;             // rows 32..63
    const int kw0 = (kr0 * 128 + kj0 * 16) ^ ((kr0 & 7) << 4);
    const int kw1 = (kr1 * 128 + kj1 * 16) ^ ((kr1 & 7) << 4);
    s8v kp0, kp1, gp0, gp1;

    auto stage_regs = [&](int t) {
        int n0 = t * KT;
        kp0 = *(const s8v*)&Xt[(size_t)(n0 + kr0) * DP + kj0 * 8];
        kp1 = *(const s8v*)&Xt[(size_t)(n0 + kr1) * DP + kj1 * 8];
        gp0 = *(const s8v*)&Gb[(size_t)kr0 * NN + n0 + kj0 * 8];   // branch-free: 64 rows
        gp1 = *(const s8v*)&Gb[(size_t)kr1 * NN + n0 + kj1 * 8];
    };
    auto lds_write = [&]() {
        *(s8v*)(K_lds + kw0) = kp0;
        *(s8v*)(K_lds + kw1) = kp1;
        *(s8v*)(G_lds + kw0) = gp0;
        *(s8v*)(G_lds + kw1) = gp1;
    };

    const int t0 = s * (NTILES / NS);
    const int tend = t0 + NTILES / NS;
    char* Pw = P_lds[wv];

    stage_regs(t0);
    lds_write();
    __syncthreads();

    #pragma unroll 1
    for (int t = t0; t < tend; ++t) {
        bool more = (t + 1 < tend);
        if (more) stage_regs(t + 1);          // global loads in flight during compute

        // ---- S = Q.K^T ----
        f4v sf[4];
        #pragma unroll
        for (int i = 0; i < 4; ++i) sf[i] = (f4v){0.f, 0.f, 0.f, 0.f};
        #pragma unroll
        for (int kt2 = 0; kt2 < 4; ++kt2)
            #pragma unroll
            for (int kb = 0; kb < 2; ++kb) {
                int off = (((kt2 * 16 + r) * 128) + kb * 64 + g * 16) ^ ((r & 7) << 4);
                s8v bf = *(const s8v*)(K_lds + off);
                sf[kt2] = __builtin_amdgcn_mfma_f32_16x16x32_bf16(qa[kb], bf, sf[kt2], 0, 0, 0);
            }

        // ---- P for keys 0..31 (kt2 = 0,1), truncating cvt ----
        #pragma unroll
        for (int kt2 = 0; kt2 < 2; ++kt2)
            #pragma unroll
            for (int reg = 0; reg < 4; ++reg) {
                float pv = __builtin_exp2f(fmaf(sf[kt2][reg], L2E, nm[reg]));
                int row = 4 * g + reg;
                int boff = ((row * 128) + kt2 * 32 + 2 * r) ^ ((row & 7) << 4);
                *(ushort*)(Pw + boff) = f2bf_trunc(pv);
            }
        // ---- Z += P.X^T kb=0 (wave-internal LDS is in-order) ----
        {
            int poff = ((r * 128) + g * 16) ^ ((r & 7) << 4);
            s8v pa = *(const s8v*)(Pw + poff);
            #pragma unroll
            for (int ot = 0; ot < 4; ++ot) {
                int goff = (((ot * 16 + r) * 128) + g * 16) ^ ((r & 7) << 4);
                s8v gf = *(const s8v*)(G_lds + goff);
                of[ot] = __builtin_amdgcn_mfma_f32_16x16x32_bf16(pa, gf, of[ot], 0, 0, 0);
            }
        }
        // ---- P for keys 32..63 (kt2 = 2,3), truncating cvt ----
        #pragma unroll
        for (int kt2 = 2; kt2 < 4; ++kt2)
            #pragma unroll
            for (int reg = 0; reg < 4; ++reg) {
                float pv = __builtin_exp2f(fmaf(sf[kt2][reg], L2E, nm[reg]));
                int row = 4 * g + reg;
                int boff = ((row * 128) + kt2 * 32 + 2 * r) ^ ((row & 7) << 4);
                *(ushort*)(Pw + boff) = f2bf_trunc(pv);
            }
        // ---- Z += P.X^T kb=1 ----
        {
            int poff = ((r * 128) + 64 + g * 16) ^ ((r & 7) << 4);
            s8v pa = *(const s8v*)(Pw + poff);
            #pragma unroll
            for (int ot = 0; ot < 4; ++ot) {
                int goff = (((ot * 16 + r) * 128) + 64 + g * 16) ^ ((r & 7) << 4);
                s8v gf = *(const s8v*)(G_lds + goff);
                of[ot] = __builtin_amdgcn_mfma_f32_16x16x32_bf16(pa, gf, of[ot], 0, 0, 0);
            }
        }

        if (more) {
            __syncthreads();                  // all waves done reading K/X^T
            lds_write();
            __syncthreads();                  // next tile staged
        }
    }

    // epilogue: unnormalized Z (+ l in col 60); k_cout applies M and divides
    int qb = q0 + wv * 16 + 4 * g;
    ushort* Ob = O_bf + ((size_t)(s * BB + b) * DP) * NN;
    #pragma unroll
    for (int ot = 0; ot < 4; ++ot) {
        int o = ot * 16 + r;
        u4v v = {f2bf_bits(of[ot][0]), f2bf_bits(of[ot][1]),
                 f2bf_bits(of[ot][2]), f2bf_bits(of[ot][3])};
        *(u4v*)&Ob[(size_t)o * NN + qb] = v;                 // coalesced 32B per r-group
    }
}

// ---------- K4 (fused combine+out): block per 32 pixels. Phase 1: sum NS splits
// into z_lds[32][61] f32 (stride 61 -> bank-free) + linv from l col (o=60).
// Phase 2: out[p] = (M[p].z)*linv + c[p] + x, written pixel-shuffled.
template <int NS>
__global__ __launch_bounds__(256) void k_cout(const ushort* __restrict__ O_bf,
                                              const float* __restrict__ Mc,
                                              const float* __restrict__ x,
                                              float* __restrict__ out) {
    __shared__ float ww[DD * DD];                      // 14.4 KB (= M)
    __shared__ float wb[DD];                           //          (= c)
    __shared__ float zlds[32][61];                     // 7.8 KB
    __shared__ float linv[32];

    int b  = blockIdx.x >> 7;                          // grid = BB*128
    int n0 = (blockIdx.x & 127) * 32;
    int tid = threadIdx.x;
    for (int i = tid; i < DD * DD; i += 256) ww[i] = Mc[i];
    if (tid < DD) wb[tid] = Mc[DD * DD + tid];

    int pix  = tid & 31;
    int ogrp = tid >> 5;                               // 0..7
    int n = n0 + pix;

    // ---- phase 1: z[pix][d] = sum_s Z_s[d][n] ; linv[pix] = 1/sum_s Z_s[60][n] ----
    const ushort* Op = O_bf + (size_t)b * DP * NN + n;
    #pragma unroll
    for (int i = 0; i < 8; ++i) {
        int o = ogrp * 8 + i;                          // 0..63
        if (o > DD) continue;                          // o<=60 processed
        float sum = 0.f;
        #pragma unroll
        for (int ss = 0; ss < NS; ++ss)
            sum += bf2f(Op[(size_t)ss * BB * DP * NN + (size_t)o * NN]);
        if (o < DD) zlds[pix][o] = sum;
        else        linv[pix] = 1.0f / sum;            // o == 60
    }
    __syncthreads();

    // ---- phase 2: 8 outputs per thread (p = 8k+ogrp), M from LDS, z from LDS ----
    float li = linv[pix];
    int oh = n >> 6, ow = n & 63;
    #pragma unroll
    for (int k = 0; k < 8; ++k) {
        int o = k * 8 + ogrp;
        if (o < DD) {
            float acc = 0.f;
            #pragma unroll
            for (int d = 0; d < DD; ++d)
                acc = fmaf(ww[o * DD + d], zlds[pix][d], acc);
            int c1 = o >> 2, r1 = (o >> 1) & 1, r2 = o & 1;
            size_t xi = ((size_t)(b * TC + c1) * HH + 2 * oh + r1) * HH + 2 * ow + r2;
            out[xi] = fmaf(acc, li, wb[o]) + x[xi];
        }
    }
}

extern "C" void kernel_launch(void* const* d_in, const int* in_sizes, int n_in,
                              void* d_out, int out_size, void* d_ws, size_t ws_size,
                              hipStream_t stream) {
    const float* x   = (const float*)d_in[0];
    const float* g_w = (const float*)d_in[1];
    const float* g_b = (const float*)d_in[2];
    const float* w_w = (const float*)d_in[3];
    const float* w_b = (const float*)d_in[4];
    float* out = (float*)d_out;

    char* ws = (char*)d_ws;
    ushort* xf2    = (ushort*)ws;                      // 2,097,152 B (B,64,N)
    ushort* xf_t   = (ushort*)(ws + 2097152);          // 2,097,152 B (B,N,64)
    float*  rnorm  = (float*)(ws + 4194304);           // 65,536 B
    uint*   mxbits = (uint*)(ws + 4259840);            // 256 B
    float*  Mc     = (float*)(ws + 4260096);           // 16,384 B  (3600 M + 60 c)
    ushort* O_bf   = (ushort*)(ws + 4276480);          // 8,388,608 B (NS=4) -> end 12,665,088
    const size_t SPLIT_NEED = 12665088;

    k_mw<<<16, 256, 0, stream>>>(g_w, g_b, w_w, w_b, Mc, mxbits);  // also zeroes mxbits
    k_prep<<<BB * NN / 256, 256, 0, stream>>>(x, xf2, xf_t, rnorm, mxbits);

    if (ws_size >= SPLIT_NEED) {
        k_attn<NSPLIT><<<NSPLIT * BB * (NN / QT), 256, 0, stream>>>(
            xf_t, xf2, rnorm, mxbits, O_bf);
        k_cout<NSPLIT><<<BB * 128, 256, 0, stream>>>(O_bf, Mc, x, out);
    } else {
        k_attn<1><<<BB * (NN / QT), 256, 0, stream>>>(
            xf_t, xf2, rnorm, mxbits, O_bf);
        k_cout<1><<<BB * 128, 256, 0, stream>>>(O_bf, Mc, x, out);
    }
}